// Round 2
// baseline (1020.939 us; speedup 1.0000x reference)
//
#include <hip/hip_runtime.h>
#include <hip/hip_bf16.h>
#include <cstddef>

// Problem constants
#define BB    8
#define CIN   64
#define HH    256
#define WW    256
#define NN    65536            // H*W per batch
#define NP    (BB*NN)          // total pixels = 524288
#define QC    64               // q channels = HEADS*QD
#define KC    16               // k channels = QD*U
#define VC    32               // v channels = VD*U
#define HEADS 4
#define QD    16

// fp32 scratch (float-element offsets within ws)
#define WQ_OFF 0               // 64*64 BN-folded Wq
#define BQ_OFF 4096            // 64
#define WK_OFF 4160            // 16*64
#define WV_OFF 5184            // 32*64 BN-folded Wv
#define BV_OFF 7232            // 32
#define WP_OFF 7264            // 16*9
#define BP_OFF 7408            // 16
#define S_OFF  7424            // B*KC softmax denominators
#define M_OFF  7552            // B*KC*VC numerators
#define SMALL_END 11648
#define FLAG_OFF 12000         // int flag: 1 = inputs are fp32, 0 = bf16
#define BF_BASE 65536          // byte offset where bf16 staging starts

typedef __hip_bfloat16 bf16;

// ---------------- K-1: detect input dtype --------------------------------
// Real bf16 N(0,1) data: no 16-bit half has exponent-field >= 134 (|v|>=128),
// and exact 0x0000 patterns are vanishingly rare. An fp32 buffer's low halves
// are near-uniform bits (~48% trigger exp>=134) or all-zero if the data was
// bf16-rounded-then-upcast. Either signature => fp32.
__global__ void k_detect(const unsigned short* __restrict xu, int* __restrict flag) {
    if (threadIdx.x == 0 && blockIdx.x == 0) {
        int big = 0, zero = 0;
        for (int i = 0; i < 256; ++i) {
            unsigned short u = xu[i];
            int e = (u >> 7) & 0xFF;
            big  += (e >= 134);
            zero += (u == 0);
        }
        *flag = (big > 4 || zero > 64) ? 1 : 0;
    }
}

__device__ __forceinline__ float ldin(const void* p, int i, int isf) {
    return isf ? ((const float*)p)[i] : (float)(((const bf16*)p)[i]);
}

// ---------------- K0: weight prep (convert to fp32, fold BN) + zero S/M ----
__global__ void k_prep(const void* __restrict wq, const void* __restrict gq,
                       const void* __restrict bq, const void* __restrict wk,
                       const void* __restrict wv, const void* __restrict gv,
                       const void* __restrict bv, const void* __restrict wp,
                       const void* __restrict bp, float* __restrict wf,
                       const int* __restrict flag) {
    int t = threadIdx.x;
    int isf = *flag;
    float rs = rsqrtf(1.0f + 1e-5f);
    for (int i = t; i < 4096; i += 256)
        wf[WQ_OFF+i] = ldin(wq, i, isf) * (ldin(gq, i>>6, isf) * rs);
    for (int i = t; i < 64;   i += 256) wf[BQ_OFF+i] = ldin(bq, i, isf);
    for (int i = t; i < 1024; i += 256) wf[WK_OFF+i] = ldin(wk, i, isf);
    for (int i = t; i < 2048; i += 256)
        wf[WV_OFF+i] = ldin(wv, i, isf) * (ldin(gv, i>>6, isf) * rs);
    for (int i = t; i < 32;   i += 256) wf[BV_OFF+i] = ldin(bv, i, isf);
    for (int i = t; i < 144;  i += 256) wf[WP_OFF+i] = ldin(wp, i, isf);
    for (int i = t; i < 16;   i += 256) wf[BP_OFF+i] = ldin(bp, i, isf);
    for (int i = t; i < SMALL_END - S_OFF; i += 256) wf[S_OFF + i] = 0.0f;  // zero S,M
}

// ---------------- K1: per-pixel q / exp(k) / v (1x1 convs, BN folded) ------
__global__ __launch_bounds__(256) void k_qkv(const void* __restrict x,
        const float* __restrict wf, const int* __restrict flag,
        bf16* __restrict qws, bf16* __restrict ekws, bf16* __restrict vws) {
    int p = blockIdx.x * 256 + threadIdx.x;          // global pixel
    int b = p >> 16, n = p & 0xFFFF;
    int isf = *flag;                                  // wave-uniform
    float xr[64];
    if (isf) {
        const float* xp = (const float*)x + (size_t)b * CIN * NN + n;
        #pragma unroll
        for (int c = 0; c < 64; ++c) xr[c] = xp[(size_t)c * NN];
    } else {
        const bf16* xp = (const bf16*)x + (size_t)b * CIN * NN + n;
        #pragma unroll
        for (int c = 0; c < 64; ++c) xr[c] = (float)xp[(size_t)c * NN];
    }

    #pragma unroll 4
    for (int o = 0; o < QC; ++o) {
        float acc = wf[BQ_OFF + o];
        const float* w = wf + WQ_OFF + o * 64;
        #pragma unroll
        for (int c = 0; c < 64; ++c) acc += w[c] * xr[c];
        qws[(size_t)o * NP + p] = (bf16)acc;
    }
    #pragma unroll 4
    for (int o = 0; o < KC; ++o) {
        float acc = 0.0f;
        const float* w = wf + WK_OFF + o * 64;
        #pragma unroll
        for (int c = 0; c < 64; ++c) acc += w[c] * xr[c];
        ekws[(size_t)o * NP + p] = (bf16)__expf(acc);   // softmax numerator
    }
    #pragma unroll 4
    for (int o = 0; o < VC; ++o) {
        float acc = wf[BV_OFF + o];
        const float* w = wf + WV_OFF + o * 64;
        #pragma unroll
        for (int c = 0; c < 64; ++c) acc += w[c] * xr[c];
        vws[(size_t)o * NP + p] = (bf16)acc;
    }
}

// ---------------- K2: lam_c numerators M[k][v] and denominators S[k] -------
#define CHUNKS 64
#define CHPIX  (NN / CHUNKS)      // 1024
#define TILE   256
__global__ __launch_bounds__(512) void k_lamc(const bf16* __restrict ekws,
        const bf16* __restrict vws, float* __restrict Sg, float* __restrict Mg) {
    __shared__ float ek[KC * 257];
    __shared__ float vv[VC * 257];
    int b = blockIdx.y, chunk = blockIdx.x, t = threadIdx.x;
    int kk = t >> 5, vi = t & 31;                 // this thread owns pair (kk, vi)
    size_t base = (size_t)b * NN + (size_t)chunk * CHPIX;
    float acc = 0.0f, sacc = 0.0f;
    for (int tile = 0; tile < CHPIX / TILE; ++tile) {
        size_t tb = base + (size_t)tile * TILE;
        for (int i = t; i < KC * TILE; i += 512) {
            int r = i >> 8, c = i & 255;
            ek[r * 257 + c] = (float)ekws[(size_t)r * NP + tb + c];
        }
        for (int i = t; i < VC * TILE; i += 512) {
            int r = i >> 8, c = i & 255;
            vv[r * 257 + c] = (float)vws[(size_t)r * NP + tb + c];
        }
        __syncthreads();
        for (int i = 0; i < TILE; ++i)
            acc += ek[kk * 257 + i] * vv[vi * 257 + i];
        if (t < KC)
            for (int i = 0; i < TILE; ++i) sacc += ek[t * 257 + i];
        __syncthreads();
    }
    atomicAdd(&Mg[(b * KC + kk) * VC + vi], acc);
    if (t < KC) atomicAdd(&Sg[b * KC + t], sacc);
}

// ---------------- K3: output = q·(lam_c+bp) + (q·Wp) * v-neighborhood -----
__global__ __launch_bounds__(256) void k_out(const bf16* __restrict qws,
        const bf16* __restrict vws, const float* __restrict wf,
        const float* __restrict Sg, const float* __restrict Mg,
        const int* __restrict flag, void* __restrict outv) {
    int y = blockIdx.x, b = blockIdx.y, xc = threadIdx.x;
    int isf = *flag;
    __shared__ float A[KC * VC];                  // lam_c[k][v] + bp[k]
    for (int i = threadIdx.x; i < KC * VC; i += 256) {
        int k = i >> 5;
        A[i] = Mg[b * KC * VC + i] / Sg[b * KC + k] + wf[BP_OFF + k];
    }
    __syncthreads();
    size_t pix = (size_t)b * NN + (size_t)y * WW + xc;

    float q[64];
    #pragma unroll
    for (int o = 0; o < 64; ++o) q[o] = (float)qws[(size_t)o * NP + pix];

    // g[h][t] = q[h,:] · Wp[:,t]  (per-pixel 3x3 filters, one per head)
    float g[HEADS][9];
    #pragma unroll
    for (int h = 0; h < HEADS; ++h)
        #pragma unroll
        for (int tn = 0; tn < 9; ++tn) {
            float acc = 0.0f;
            #pragma unroll
            for (int k = 0; k < 16; ++k) acc += q[h * 16 + k] * wf[WP_OFF + k * 9 + tn];
            g[h][tn] = acc;
        }

    for (int v = 0; v < VC; ++v) {
        float Ac[16];
        #pragma unroll
        for (int k = 0; k < 16; ++k) Ac[k] = A[k * VC + v];
        float vn[9];
        const bf16* vp = vws + (size_t)v * NP + (size_t)b * NN;
        #pragma unroll
        for (int dy = -1; dy <= 1; ++dy)
            #pragma unroll
            for (int dx = -1; dx <= 1; ++dx) {
                int yy = y + dy, xx = xc + dx;
                bool ok = (yy >= 0) & (yy < HH) & (xx >= 0) & (xx < WW);
                vn[(dy + 1) * 3 + dx + 1] = ok ? (float)vp[yy * WW + xx] : 0.0f;
            }
        #pragma unroll
        for (int h = 0; h < HEADS; ++h) {
            float acc = 0.0f;
            #pragma unroll
            for (int k = 0; k < 16; ++k) acc += q[h * 16 + k] * Ac[k];
            #pragma unroll
            for (int tn = 0; tn < 9; ++tn) acc += g[h][tn] * vn[tn];
            size_t idx = ((size_t)(b * HEADS + h) * VC + v) * NN + (size_t)y * WW + xc;
            if (isf) ((float*)outv)[idx] = acc;
            else     ((bf16*)outv)[idx] = (bf16)acc;
        }
    }
}

extern "C" void kernel_launch(void* const* d_in, const int* in_sizes, int n_in,
                              void* d_out, int out_size, void* d_ws, size_t ws_size,
                              hipStream_t stream) {
    float* wf = (float*)d_ws;
    int* flag = (int*)wf + FLAG_OFF;
    bf16* qws  = (bf16*)((char*)d_ws + BF_BASE);
    bf16* ekws = qws + (size_t)QC * NP;
    bf16* vws  = ekws + (size_t)KC * NP;
    // ws usage: 65536 + (64+16+32)*524288*2 bytes ≈ 117.5 MB

    k_detect<<<1, 64, 0, stream>>>((const unsigned short*)d_in[0], flag);
    k_prep<<<1, 256, 0, stream>>>(d_in[1], d_in[2], d_in[3], d_in[4], d_in[5],
                                  d_in[6], d_in[7], d_in[8], d_in[9], wf, flag);
    k_qkv<<<NP / 256, 256, 0, stream>>>(d_in[0], wf, flag, qws, ekws, vws);
    k_lamc<<<dim3(CHUNKS, BB), 512, 0, stream>>>(ekws, vws, wf + S_OFF, wf + M_OFF);
    k_out<<<dim3(HH, BB), 256, 0, stream>>>(qws, vws, wf, wf + S_OFF, wf + M_OFF,
                                            flag, d_out);
}